// Round 6
// baseline (3252.370 us; speedup 1.0000x reference)
//
#include <hip/hip_runtime.h>
#include <hip/hip_bf16.h>

typedef __bf16 bf16x8 __attribute__((ext_vector_type(8)));
typedef __bf16 bf16x4 __attribute__((ext_vector_type(4)));
typedef float  f32x4  __attribute__((ext_vector_type(4)));
typedef unsigned int u32;
typedef unsigned long long u64;

static __device__ __forceinline__ f32x4 mfma16(bf16x8 a, bf16x8 b, f32x4 c) {
    return __builtin_amdgcn_mfma_f32_16x16x32_bf16(a, b, c, 0, 0, 0);
}
static __device__ __forceinline__ f32x4 mfma16v(bf16x8 a, f32x4 bw, f32x4 c) {
    return mfma16(a, __builtin_bit_cast(bf16x8, bw), c);
}

#define TLEN 512
#define IDIM 128
#define FDIM 512
#define MDIM 512
#define ODIM 128
#define BC   16      // batch rows per group
#define NGRP 16      // batch groups
#define NCU  8       // WGs per group; CU p owns 64 F-cols, 64 M-cols, 64 G3-K
#define PSTR 520     // m LDS stride (bf16): 2-way bank alias (free)
#define FSTR 72      // f_own LDS stride
#define XSTR 136

// ---- workspace byte offsets ----
#define WS_WI   0
#define WS_W2F  (WS_WI  + FDIM*IDIM*2)
#define WS_W2M  (WS_W2F + FDIM*MDIM*2)
#define WS_WF2  (WS_W2M + MDIM*MDIM*2)
#define WS_WO   (WS_WF2 + MDIM*FDIM*2)
#define WS_B1   (WS_WO  + ODIM*MDIM*2)
#define WS_B23  (WS_B1  + FDIM*4)
#define WS_CTR  (WS_B23 + MDIM*4)
#define WS_MBUF (WS_CTR + NGRP*64*4)    // f32 [NGRP][3][BC][MDIM]

#define N_WI  (FDIM*IDIM)
#define N_W2F (FDIM*MDIM)
#define N_W2M (MDIM*MDIM)
#define N_WF2 (MDIM*FDIM)
#define N_WO  (ODIM*MDIM)
#define N_MB  (NGRP*3*BC*MDIM)          // 393216 f32

// ---------------------------------------------------------------------------
// Prep: bf16-pack weights, fuse biases, zero ctrs, init m-buffers:
//   mbuf[g][0] = m0 rows, mbuf[g][1] = mbuf[g][2] = 0.
// ---------------------------------------------------------------------------
__global__ __launch_bounds__(256) void lmn_prep(
    const float* __restrict__ Wi2f, const float* __restrict__ Wm2f,
    const float* __restrict__ Wm2m, const float* __restrict__ Wf2m,
    const float* __restrict__ Wout, const float* __restrict__ m0,
    const float* __restrict__ bi2f, const float* __restrict__ bm2f,
    const float* __restrict__ bf2m, const float* __restrict__ bm2m,
    __bf16* __restrict__ WI, __bf16* __restrict__ W2F, __bf16* __restrict__ W2M,
    __bf16* __restrict__ WF2, __bf16* __restrict__ WO,
    float* __restrict__ b1, float* __restrict__ b23,
    u32* __restrict__ ctrs, float* __restrict__ mbuf)
{
    int i = blockIdx.x * 256 + threadIdx.x;
    if (i < N_WI)  { WI[i]  = (__bf16)Wi2f[i]; return; }  i -= N_WI;
    if (i < N_W2F) { W2F[i] = (__bf16)Wm2f[i]; return; }  i -= N_W2F;
    if (i < N_W2M) { W2M[i] = (__bf16)Wm2m[i]; return; }  i -= N_W2M;
    if (i < N_WF2) { WF2[i] = (__bf16)Wf2m[i]; return; }  i -= N_WF2;
    if (i < N_WO)  { WO[i]  = (__bf16)Wout[i]; return; }  i -= N_WO;
    if (i < FDIM)  { b1[i]  = bi2f[i] + bm2f[i]; return; } i -= FDIM;
    if (i < MDIM)  { b23[i] = bf2m[i] + bm2m[i]; return; } i -= MDIM;
    if (i < NGRP * 64) { ctrs[i] = 0u; return; }           i -= NGRP * 64;
    if (i < N_MB) {
        int g   = i / (3 * BC * MDIM);
        int r3  = i - g * (3 * BC * MDIM);
        int buf = r3 >> 13;             // /8192
        int rc  = r3 & 8191;
        int r   = rc >> 9, c = rc & 511;
        mbuf[i] = (buf == 0) ? m0[(size_t)(g * BC + r) * MDIM + c] : 0.f;
    }
}

// ---------------------------------------------------------------------------
// Scan: 128 WGs x 512 threads (8 waves, 2/SIMD). Group g = 8 WGs, rows
// 16g..16g+15. ONE group event per step (m'-reduction at the LLC):
//   gather m_t (f32, agent loads) -> bf16 LDS
//   G1 waves (w<4): f_own = tanh(x@WI_own + m@W2F_own + b1_own) -> flds
//   G23 waves:      G2 = m@W2M_own  (runs concurrently)
//   barrier; G23: P = f_own @ WF2[:, own 64 K] (full 512-wide partial),
//   atomicAdd(f32) P and G2+b23 into mbuf[t+1]; G1: zero mbuf[t+2] own slice,
//   stage x_{t+1}; vmcnt drain -> barrier -> ctr arrive -> tid0 spin -> release.
// Weights: shared-name role arrays wA/wB (128 VGPR), pinned vs remat.
// ---------------------------------------------------------------------------
__global__ __launch_bounds__(512, 2) void lmn_scan(
    const float* __restrict__ x,
    const __bf16* __restrict__ WI, const __bf16* __restrict__ W2F,
    const __bf16* __restrict__ W2M, const __bf16* __restrict__ WF2,
    const __bf16* __restrict__ WO,
    const float* __restrict__ b1, const float* __restrict__ b23,
    const float* __restrict__ bout,
    u32* __restrict__ ctrs, float* __restrict__ mbuf_all,
    float* __restrict__ out)
{
    __shared__ __bf16 mlds[BC][PSTR];
    __shared__ __bf16 flds[BC][FSTR];
    __shared__ __bf16 xlds[2][BC][XSTR];

    const int tid  = threadIdx.x;
    const int lane = tid & 63;
    const int w    = tid >> 6;        // 0..7
    const int wq   = w & 3;
    const int l15  = lane & 15;
    const int l4   = lane >> 4;
    const int koff = 8 * l4;
    const bool isG1 = (w < 4);

    const int b = blockIdx.x;
    const int g = b & 15;             // group
    const int p = b >> 4;             // 0..7 position
    const int row0 = g * BC;

    u32*   ctr = ctrs + g * 64;
    float* mb  = mbuf_all + (size_t)g * 3 * BC * MDIM;   // [3][16][512]

    const int c0 = 64 * p + 16 * wq + l15;   // G1 f-col / G23 G2 m-col

    // ---- resident weights: wA/wB shared-name role arrays (128 VGPR) ----
    f32x4 wA[16], wB[16];
    {
        const __bf16* rA = (isG1 ? W2F : W2M) + (size_t)c0 * MDIM;
        #pragma unroll
        for (int j = 0; j < 16; ++j)
            wA[j] = *(const f32x4*)&rA[j * 32 + koff];
        if (isG1) {
            const __bf16* rB = WI + (size_t)c0 * IDIM;
            #pragma unroll
            for (int j = 0; j < 4; ++j) wB[j] = *(const f32x4*)&rB[j * 32 + koff];
            #pragma unroll
            for (int j = 4; j < 16; ++j) wB[j] = f32x4{0, 0, 0, 0};
        } else {
            // wB[2*nt+jj] = WF2[col=128*wq+16*nt+l15][64*p + 32*jj + koff]
            #pragma unroll
            for (int nt = 0; nt < 8; ++nt)
                #pragma unroll
                for (int jj = 0; jj < 2; ++jj)
                    wB[2 * nt + jj] = *(const f32x4*)
                        &WF2[(size_t)(128 * wq + 16 * nt + l15) * FDIM
                             + 64 * p + 32 * jj + koff];
        }
        #pragma unroll
        for (int j = 0; j < 16; ++j)
            asm volatile("" : "+v"(wA[j]), "+v"(wB[j]));   // pin: no remat
    }
    const float b1r = b1[c0];
    const float b2r = b23[c0];

    // ---- stage x[0] ----
    if (tid < 256) {
        int rr = tid >> 4, c8 = (tid & 15) << 3;
        const float* xs = &x[(size_t)(row0 + rr) * TLEN * IDIM + c8];
        float4 v0 = ((const float4*)xs)[0], v1 = ((const float4*)xs)[1];
        *(bf16x8*)&xlds[0][rr][c8] =
            bf16x8{(__bf16)v0.x, (__bf16)v0.y, (__bf16)v0.z, (__bf16)v0.w,
                   (__bf16)v1.x, (__bf16)v1.y, (__bf16)v1.z, (__bf16)v1.w};
    }

    const int grow = tid >> 5;              // gather row 0..15
    const int gcol = (tid & 31) * 16;       // gather col base

    int ia = 0;                             // read buf, ib=(ia+1)%3, ic=(ia+2)%3
    for (int t = 0; t < TLEN; ++t) {
        const int ib = (ia == 2) ? 0 : ia + 1;
        const int ic = (ib == 2) ? 0 : ib + 1;

        // ---- gather m_t: f32 agent loads -> bf16 -> mlds ----
        {
            const float* src = mb + ia * (BC * MDIM) + grow * MDIM + gcol;
            float2 v[8];
            #pragma unroll
            for (int j = 0; j < 8; ++j) {
                u64 raw = __hip_atomic_load((const u64*)&src[2 * j],
                                            __ATOMIC_RELAXED, __HIP_MEMORY_SCOPE_AGENT);
                v[j] = __builtin_bit_cast(float2, raw);
            }
            bf16x8 o0 = {(__bf16)v[0].x, (__bf16)v[0].y, (__bf16)v[1].x, (__bf16)v[1].y,
                         (__bf16)v[2].x, (__bf16)v[2].y, (__bf16)v[3].x, (__bf16)v[3].y};
            bf16x8 o1 = {(__bf16)v[4].x, (__bf16)v[4].y, (__bf16)v[5].x, (__bf16)v[5].y,
                         (__bf16)v[6].x, (__bf16)v[6].y, (__bf16)v[7].x, (__bf16)v[7].y};
            *(bf16x8*)&mlds[grow][gcol]     = o0;
            *(bf16x8*)&mlds[grow][gcol + 8] = o1;
        }
        __syncthreads();                 // B0: mlds = m_t

        // ---- phase A ----
        if (isG1) {                      // f_own = tanh(x@WI + m@W2F + b1)
            f32x4 ae = {0,0,0,0}, ao = {0,0,0,0};
            #pragma unroll
            for (int j = 0; j < 4; ++j) {
                bf16x8 ax = *(const bf16x8*)&xlds[t & 1][l15][j * 32 + koff];
                if (j & 1) ao = mfma16v(ax, wB[j], ao);
                else       ae = mfma16v(ax, wB[j], ae);
            }
            #pragma unroll
            for (int j = 0; j < 16; ++j) {
                bf16x8 am = *(const bf16x8*)&mlds[l15][j * 32 + koff];
                if (j & 1) ao = mfma16v(am, wA[j], ao);
                else       ae = mfma16v(am, wA[j], ae);
            }
            f32x4 fa = ae + ao;
            #pragma unroll
            for (int r = 0; r < 4; ++r)
                flds[4 * l4 + r][16 * wq + l15] = (__bf16)tanhf(fa[r] + b1r);
        }
        f32x4 g2e = {0,0,0,0}, g2o = {0,0,0,0};
        if (!isG1) {                     // G2 = m@W2M (own cols)
            #pragma unroll
            for (int j = 0; j < 16; ++j) {
                bf16x8 am = *(const bf16x8*)&mlds[l15][j * 32 + koff];
                if (j & 1) g2o = mfma16v(am, wA[j], g2o);
                else       g2e = mfma16v(am, wA[j], g2e);
            }
        }
        __syncthreads();                 // B1: flds = f_own

        // ---- phase B ----
        float* dst = mb + ib * (BC * MDIM);
        if (!isG1) {
            // P = f_own @ WF2[:, own K]  (8 n-tiles x K=64)
            f32x4 pacc[8];
            #pragma unroll
            for (int nt = 0; nt < 8; ++nt) pacc[nt] = f32x4{0, 0, 0, 0};
            #pragma unroll
            for (int jj = 0; jj < 2; ++jj) {
                bf16x8 af = *(const bf16x8*)&flds[l15][32 * jj + koff];
                #pragma unroll
                for (int nt = 0; nt < 8; ++nt)
                    pacc[nt] = mfma16v(af, wB[2 * nt + jj], pacc[nt]);
            }
            #pragma unroll
            for (int nt = 0; nt < 8; ++nt) {
                int col = 128 * wq + 16 * nt + l15;
                #pragma unroll
                for (int r = 0; r < 4; ++r)
                    atomicAdd(&dst[(4 * l4 + r) * MDIM + col], pacc[nt][r]);
            }
            f32x4 g2 = g2e + g2o;
            #pragma unroll
            for (int r = 0; r < 4; ++r)
                atomicAdd(&dst[(4 * l4 + r) * MDIM + c0], g2[r] + b2r);
        } else {
            // zero mbuf[ic] own slice (16 x 64 f32)
            {
                float* z = mb + ic * (BC * MDIM) + (tid >> 4) * MDIM + 64 * p
                           + ((tid & 15) << 2);
                __hip_atomic_store((u64*)&z[0], 0ull,
                                   __ATOMIC_RELAXED, __HIP_MEMORY_SCOPE_AGENT);
                __hip_atomic_store((u64*)&z[2], 0ull,
                                   __ATOMIC_RELAXED, __HIP_MEMORY_SCOPE_AGENT);
            }
            // stage x_{t+1}
            if (t + 1 < TLEN) {
                int rr = tid >> 4, c8 = (tid & 15) << 3;
                const float* xs = &x[((size_t)(row0 + rr) * TLEN + (t + 1)) * IDIM + c8];
                float4 v0 = ((const float4*)xs)[0], v1 = ((const float4*)xs)[1];
                *(bf16x8*)&xlds[(t + 1) & 1][rr][c8] =
                    bf16x8{(__bf16)v0.x, (__bf16)v0.y, (__bf16)v0.z, (__bf16)v0.w,
                           (__bf16)v1.x, (__bf16)v1.y, (__bf16)v1.z, (__bf16)v1.w};
            }
        }
        asm volatile("s_waitcnt vmcnt(0)" ::: "memory");
        __syncthreads();                 // B2: all global ops drained
        if (tid == 0) {
            __hip_atomic_fetch_add(ctr, 1u, __ATOMIC_RELAXED, __HIP_MEMORY_SCOPE_AGENT);
            u32 tgt = 8u * (u32)t + 8u;
            while (__hip_atomic_load(ctr, __ATOMIC_RELAXED, __HIP_MEMORY_SCOPE_AGENT) < tgt)
                __builtin_amdgcn_s_sleep(1);
        }
        __syncthreads();                 // B3: release, m_{t+1} complete
        ia = ib;
    }

    // ---- epilogue: p==0 WG computes out = m_T @ Wout^T + bout ----
    if (p == 0) {
        {
            const float* src = mb + ia * (BC * MDIM) + grow * MDIM + gcol;
            float2 v[8];
            #pragma unroll
            for (int j = 0; j < 8; ++j) {
                u64 raw = __hip_atomic_load((const u64*)&src[2 * j],
                                            __ATOMIC_RELAXED, __HIP_MEMORY_SCOPE_AGENT);
                v[j] = __builtin_bit_cast(float2, raw);
            }
            bf16x8 o0 = {(__bf16)v[0].x, (__bf16)v[0].y, (__bf16)v[1].x, (__bf16)v[1].y,
                         (__bf16)v[2].x, (__bf16)v[2].y, (__bf16)v[3].x, (__bf16)v[3].y};
            bf16x8 o1 = {(__bf16)v[4].x, (__bf16)v[4].y, (__bf16)v[5].x, (__bf16)v[5].y,
                         (__bf16)v[6].x, (__bf16)v[6].y, (__bf16)v[7].x, (__bf16)v[7].y};
            *(bf16x8*)&mlds[grow][gcol]     = o0;
            *(bf16x8*)&mlds[grow][gcol + 8] = o1;
        }
        __syncthreads();
        const int oc = 16 * w + l15;
        const __bf16* ro = WO + (size_t)oc * MDIM;
        f32x4 oe = {0,0,0,0}, oo = {0,0,0,0};
        #pragma unroll
        for (int j = 0; j < 16; ++j) {
            bf16x8 am = *(const bf16x8*)&mlds[l15][j * 32 + koff];
            bf16x8 bw = *(const bf16x8*)&ro[j * 32 + koff];
            if (j & 1) oo = mfma16(am, bw, oo); else oe = mfma16(am, bw, oe);
        }
        f32x4 oa = oe + oo;
        const float bo = bout[oc];
        #pragma unroll
        for (int r = 0; r < 4; ++r)
            out[(size_t)(row0 + 4 * l4 + r) * ODIM + oc] = oa[r] + bo;
    }
}

extern "C" void kernel_launch(void* const* d_in, const int* in_sizes, int n_in,
                              void* d_out, int out_size, void* d_ws, size_t ws_size,
                              hipStream_t stream)
{
    const float* x    = (const float*)d_in[0];
    const float* m0   = (const float*)d_in[1];
    const float* Wi2f = (const float*)d_in[2];
    const float* bi2f = (const float*)d_in[3];
    const float* Wm2f = (const float*)d_in[4];
    const float* bm2f = (const float*)d_in[5];
    const float* Wf2m = (const float*)d_in[6];
    const float* bf2m = (const float*)d_in[7];
    const float* Wm2m = (const float*)d_in[8];
    const float* bm2m = (const float*)d_in[9];
    const float* Wout = (const float*)d_in[10];
    const float* bout = (const float*)d_in[11];

    char* ws = (char*)d_ws;
    __bf16* WI  = (__bf16*)(ws + WS_WI);
    __bf16* W2F = (__bf16*)(ws + WS_W2F);
    __bf16* W2M = (__bf16*)(ws + WS_W2M);
    __bf16* WF2 = (__bf16*)(ws + WS_WF2);
    __bf16* WO  = (__bf16*)(ws + WS_WO);
    float*  b1  = (float*)(ws + WS_B1);
    float*  b23 = (float*)(ws + WS_B23);
    u32*    ctr = (u32*)(ws + WS_CTR);
    float*  mbf = (float*)(ws + WS_MBUF);

    const int prep_total = N_WI + N_W2F + N_W2M + N_WF2 + N_WO
                         + FDIM + MDIM + NGRP * 64 + N_MB;
    lmn_prep<<<(prep_total + 255) / 256, 256, 0, stream>>>(
        Wi2f, Wm2f, Wm2m, Wf2m, Wout, m0, bi2f, bm2f, bf2m, bm2m,
        WI, W2F, W2M, WF2, WO, b1, b23, ctr, mbf);

    lmn_scan<<<NGRP * NCU, 512, 0, stream>>>(
        x, WI, W2F, W2M, WF2, WO, b1, b23, bout, ctr, mbf, (float*)d_out);
}

// Round 7
// 2392.388 us; speedup vs baseline: 1.3595x; 1.3595x over previous
//
#include <hip/hip_runtime.h>
#include <hip/hip_bf16.h>

typedef __bf16 bf16x8 __attribute__((ext_vector_type(8)));
typedef __bf16 bf16x4 __attribute__((ext_vector_type(4)));
typedef float  f32x4  __attribute__((ext_vector_type(4)));
typedef unsigned int u32;
typedef unsigned long long u64;

// ---- inline-asm MFMA with B operand in AGPR ----------------------------
// mfma_z: chain start, C = inline constant 0 (no init hazard), D early-clobber.
// mfma_a: accumulate, D tied to C ("+v").
// Weights pinned to AGPRs once ("+a") -> allocator keeps them resident:
// nothing else competes for the AGPR file on gfx950.
static __device__ __forceinline__ void mfma_z(f32x4& d, bf16x8 a, const f32x4& b) {
    asm("v_mfma_f32_16x16x32_bf16 %0, %1, %2, 0"
        : "=&v"(d) : "v"(a), "a"(b));
}
static __device__ __forceinline__ void mfma_a(f32x4& d, bf16x8 a, const f32x4& b) {
    asm("v_mfma_f32_16x16x32_bf16 %0, %1, %2, %0"
        : "+v"(d) : "v"(a), "a"(b));
}
// hazard guard: MFMA D -> VALU read needs ~16 cycles on the MAI pipe
#define ACC_GUARD(e, o) asm volatile("s_nop 7\n\ts_nop 7" : "+v"(e), "+v"(o))

static __device__ __forceinline__ f32x4 mfma16(bf16x8 a, bf16x8 b, f32x4 c) {
    return __builtin_amdgcn_mfma_f32_16x16x32_bf16(a, b, c, 0, 0, 0);
}

#define TLEN 512
#define IDIM 128
#define FDIM 512
#define MDIM 512
#define ODIM 128
#define BC   16      // batch rows per group
#define NGRP 16      // batch groups
#define NCU  8       // WGs per group; CU p owns 64 F-cols + 64 M-cols
#define PSTR 520     // m/f LDS stride (bf16): 2-way bank alias (free)
#define XSTR 136

// ---- workspace byte offsets ----
#define WS_WI   0
#define WS_W2F  (WS_WI  + FDIM*IDIM*2)
#define WS_W2M  (WS_W2F + FDIM*MDIM*2)
#define WS_WF2  (WS_W2M + MDIM*MDIM*2)
#define WS_WO   (WS_WF2 + MDIM*FDIM*2)
#define WS_B1   (WS_WO  + ODIM*MDIM*2)
#define WS_B23  (WS_B1  + FDIM*4)
#define WS_CTR  (WS_B23 + MDIM*4)
#define WS_FBUF (WS_CTR + NGRP*64*4)
#define WS_MBUF (WS_FBUF + NGRP*BC*FDIM*2)

#define N_WI  (FDIM*IDIM)
#define N_W2F (FDIM*MDIM)
#define N_W2M (MDIM*MDIM)
#define N_WF2 (MDIM*FDIM)
#define N_WO  (ODIM*MDIM)

__global__ __launch_bounds__(256) void lmn_prep(
    const float* __restrict__ Wi2f, const float* __restrict__ Wm2f,
    const float* __restrict__ Wm2m, const float* __restrict__ Wf2m,
    const float* __restrict__ Wout,
    const float* __restrict__ bi2f, const float* __restrict__ bm2f,
    const float* __restrict__ bf2m, const float* __restrict__ bm2m,
    __bf16* __restrict__ WI, __bf16* __restrict__ W2F, __bf16* __restrict__ W2M,
    __bf16* __restrict__ WF2, __bf16* __restrict__ WO,
    float* __restrict__ b1, float* __restrict__ b23, u32* __restrict__ ctrs)
{
    int i = blockIdx.x * 256 + threadIdx.x;
    if (i < N_WI)  { WI[i]  = (__bf16)Wi2f[i]; return; }  i -= N_WI;
    if (i < N_W2F) { W2F[i] = (__bf16)Wm2f[i]; return; }  i -= N_W2F;
    if (i < N_W2M) { W2M[i] = (__bf16)Wm2m[i]; return; }  i -= N_W2M;
    if (i < N_WF2) { WF2[i] = (__bf16)Wf2m[i]; return; }  i -= N_WF2;
    if (i < N_WO)  { WO[i]  = (__bf16)Wout[i]; return; }  i -= N_WO;
    if (i < FDIM)  { b1[i]  = bi2f[i] + bm2f[i]; return; } i -= FDIM;
    if (i < MDIM)  { b23[i] = bf2m[i] + bm2m[i]; return; } i -= MDIM;
    if (i < NGRP * 64) { ctrs[i] = 0u; return; }
}

// ---------------------------------------------------------------------------
// R5 structure (two exchange events/step, relaxed u64 agent atomics, one
// arrival + one spinner per WG) + AGPR-resident weights via inline-asm MFMA.
// Wave roles: w<4 -> G1 (f), w>=4 -> G23 (m'). 32 weight frags/lane in AGPR.
// ---------------------------------------------------------------------------
__global__ __launch_bounds__(512, 2) void lmn_scan(
    const float* __restrict__ x, const float* __restrict__ m0,
    const __bf16* __restrict__ WI, const __bf16* __restrict__ W2F,
    const __bf16* __restrict__ W2M, const __bf16* __restrict__ WF2,
    const __bf16* __restrict__ WO,
    const float* __restrict__ b1, const float* __restrict__ b23,
    const float* __restrict__ bout,
    u32* __restrict__ ctrs, __bf16* __restrict__ fbuf_all,
    __bf16* __restrict__ mbuf_all, float* __restrict__ out)
{
    __shared__ __bf16 mlds[BC][PSTR];
    __shared__ __bf16 flds[BC][PSTR];
    __shared__ __bf16 xlds[2][BC][XSTR];

    const int tid  = threadIdx.x;
    const int lane = tid & 63;
    const int w    = tid >> 6;        // 0..7
    const int wq   = w & 3;
    const int l15  = lane & 15;
    const int l4   = lane >> 4;
    const int koff = 8 * l4;
    const bool isG1 = (w < 4);

    const int b = blockIdx.x;
    const int g = b & 15;             // group (members at bid=16p+g)
    const int p = b >> 4;             // 0..7 position in group
    const int row0 = g * BC;

    u32*    ctr  = ctrs + g * 64;
    __bf16* fbuf = fbuf_all + (size_t)g * BC * FDIM;
    __bf16* mbuf = mbuf_all + (size_t)g * BC * MDIM;

    const int c0 = 64 * p + 16 * wq + l15;   // lane's output column

    // ---- resident weights -> AGPRs (32 frags = 128 AGPR per lane) ----
    f32x4 wA[16], wB[16];
    {
        const __bf16* rA = (isG1 ? W2F : W2M) + (size_t)c0 * MDIM;
        #pragma unroll
        for (int j = 0; j < 16; ++j)
            wA[j] = *(const f32x4*)&rA[((2 * p + j) & 15) * 32 + koff];
        if (isG1) {
            const __bf16* rB = WI + (size_t)c0 * IDIM;
            #pragma unroll
            for (int j = 0; j < 4; ++j) wB[j] = *(const f32x4*)&rB[j * 32 + koff];
            #pragma unroll
            for (int j = 4; j < 16; ++j) wB[j] = f32x4{0, 0, 0, 0};
        } else {
            const __bf16* rB = WF2 + (size_t)c0 * FDIM;
            #pragma unroll
            for (int j = 0; j < 16; ++j)
                wB[j] = *(const f32x4*)&rB[((2 * p + j) & 15) * 32 + koff];
        }
        #pragma unroll
        for (int j = 0; j < 16; ++j)
            asm volatile("" : "+a"(wA[j]), "+a"(wB[j]));   // pin into AGPR file
    }
    const float br = isG1 ? b1[c0] : b23[c0];

    // ---- init LDS: full m0, x[0] ----
    for (int u = tid; u < BC * MDIM / 4; u += 512) {
        int r = u >> 7, c = (u & 127) * 4;
        float4 v = *(const float4*)&m0[(size_t)(row0 + r) * MDIM + c];
        *(bf16x4*)&mlds[r][c] = bf16x4{(__bf16)v.x, (__bf16)v.y, (__bf16)v.z, (__bf16)v.w};
    }
    {
        int r = tid >> 5, c = (tid & 31) * 4;
        float4 v = *(const float4*)&x[(size_t)(row0 + r) * TLEN * IDIM + c];
        *(bf16x4*)&xlds[0][r][c] = bf16x4{(__bf16)v.x, (__bf16)v.y, (__bf16)v.z, (__bf16)v.w};
    }
    __syncthreads();

    // ---- seed acc for t=0 ----
    f32x4 accE, accO;
    if (isG1) {
        bf16x8 ax0 = *(const bf16x8*)&xlds[0][l15][0 * 32 + koff];
        bf16x8 ax1 = *(const bf16x8*)&xlds[0][l15][1 * 32 + koff];
        bf16x8 ax2 = *(const bf16x8*)&xlds[0][l15][2 * 32 + koff];
        bf16x8 ax3 = *(const bf16x8*)&xlds[0][l15][3 * 32 + koff];
        mfma_z(accE, ax0, wB[0]);  mfma_z(accO, ax1, wB[1]);
        mfma_a(accE, ax2, wB[2]);  mfma_a(accO, ax3, wB[3]);
        bf16x8 am0 = *(const bf16x8*)&mlds[l15][((2 * p + 0) & 15) * 32 + koff];
        bf16x8 am1 = *(const bf16x8*)&mlds[l15][((2 * p + 1) & 15) * 32 + koff];
        mfma_a(accE, am0, wA[0]);  mfma_a(accO, am1, wA[1]);
    } else {
        bf16x8 am0 = *(const bf16x8*)&mlds[l15][((2 * p + 0) & 15) * 32 + koff];
        bf16x8 am1 = *(const bf16x8*)&mlds[l15][((2 * p + 1) & 15) * 32 + koff];
        mfma_z(accE, am0, wA[0]);  mfma_z(accO, am1, wA[1]);
    }

    for (int t = 0; t < TLEN; ++t) {
        // ---- A-phase (uniform): 14 peer m k-frags ----
        #pragma unroll
        for (int j = 2; j < 16; ++j) {
            bf16x8 am = *(const bf16x8*)&mlds[l15][((2 * p + j) & 15) * 32 + koff];
            if (j & 1) mfma_a(accO, am, wA[j]);
            else       mfma_a(accE, am, wA[j]);
        }
        if (isG1) {                   // f = tanh(pre + b1) -> own cols of flds
            ACC_GUARD(accE, accO);
            f32x4 fa = accE + accO;
            #pragma unroll
            for (int r = 0; r < 4; ++r)
                flds[4 * l4 + r][c0] = (__bf16)tanhf(fa[r] + br);
        }
        __syncthreads();              // S1: f-own in LDS

        if (tid < 256) {              // export f own block (256 u64)
            int rr = tid >> 4, c4 = (tid & 15) << 2;
            u64 v = *(const u64*)&flds[rr][64 * p + c4];
            __hip_atomic_store((u64*)&fbuf[rr * FDIM + 64 * p + c4], v,
                               __ATOMIC_RELAXED, __HIP_MEMORY_SCOPE_AGENT);
        }
        asm volatile("s_waitcnt vmcnt(0)" ::: "memory");
        __syncthreads();              // S2: exports drained
        if (tid == 0)                 // arrive A
            __hip_atomic_fetch_add(ctr, 1u, __ATOMIC_RELAXED, __HIP_MEMORY_SCOPE_AGENT);

        // RTT window A: stage x_{t+1} (G1 threads) + own-block G3 (G23 waves)
        if (tid < 256 && t + 1 < TLEN) {
            int rr = tid >> 4, c8 = (tid & 15) << 3;
            const float* xs = &x[((size_t)(row0 + rr) * TLEN + (t + 1)) * IDIM + c8];
            float4 v0 = ((const float4*)xs)[0], v1 = ((const float4*)xs)[1];
            *(bf16x8*)&xlds[(t + 1) & 1][rr][c8] =
                bf16x8{(__bf16)v0.x, (__bf16)v0.y, (__bf16)v0.z, (__bf16)v0.w,
                       (__bf16)v1.x, (__bf16)v1.y, (__bf16)v1.z, (__bf16)v1.w};
        }
        if (!isG1) {                  // continue G23 chain: own-block f
            bf16x8 af0 = *(const bf16x8*)&flds[l15][((2 * p + 0) & 15) * 32 + koff];
            bf16x8 af1 = *(const bf16x8*)&flds[l15][((2 * p + 1) & 15) * 32 + koff];
            mfma_a(accE, af0, wB[0]);
            mfma_a(accO, af1, wB[1]);
        }
        if (tid == 0) {               // wait A
            u32 tgt = 16u * (u32)t + 8u;
            while (__hip_atomic_load(ctr, __ATOMIC_RELAXED, __HIP_MEMORY_SCOPE_AGENT) < tgt)
                __builtin_amdgcn_s_sleep(1);
        }
        __syncthreads();              // S3: release A
        for (int s = tid; s < 1792; s += 512) {   // gather peers' f (14KB)
            int j = 1 + (s >> 8);
            int k = s & 255;
            int q = (p + j) & 7;
            int rr = k >> 4, c4 = (k & 15) << 2;
            u64 v = __hip_atomic_load((const u64*)&fbuf[rr * FDIM + 64 * q + c4],
                                      __ATOMIC_RELAXED, __HIP_MEMORY_SCOPE_AGENT);
            *(u64*)&flds[rr][64 * q + c4] = v;
        }
        __syncthreads();              // S4: flds full

        // ---- B-phase ----
        if (!isG1) {                  // peer G3 + m' write
            #pragma unroll
            for (int j = 2; j < 16; ++j) {
                bf16x8 af = *(const bf16x8*)&flds[l15][((2 * p + j) & 15) * 32 + koff];
                if (j & 1) mfma_a(accO, af, wB[j]);
                else       mfma_a(accE, af, wB[j]);
            }
            ACC_GUARD(accE, accO);
            f32x4 ma = accE + accO;
            #pragma unroll
            for (int r = 0; r < 4; ++r)
                mlds[4 * l4 + r][c0] = (__bf16)(ma[r] + br);
        } else {                      // fresh chain: x-part seed for t+1
            if (t + 1 < TLEN) {
                bf16x8 ax0 = *(const bf16x8*)&xlds[(t + 1) & 1][l15][0 * 32 + koff];
                bf16x8 ax1 = *(const bf16x8*)&xlds[(t + 1) & 1][l15][1 * 32 + koff];
                bf16x8 ax2 = *(const bf16x8*)&xlds[(t + 1) & 1][l15][2 * 32 + koff];
                bf16x8 ax3 = *(const bf16x8*)&xlds[(t + 1) & 1][l15][3 * 32 + koff];
                mfma_z(accE, ax0, wB[0]);  mfma_z(accO, ax1, wB[1]);
                mfma_a(accE, ax2, wB[2]);  mfma_a(accO, ax3, wB[3]);
            }
        }
        __syncthreads();              // S5: m'-own in LDS

        if (tid >= 256) {             // export m' own block
            int u = tid - 256;
            int rr = u >> 4, c4 = (u & 15) << 2;
            u64 v = *(const u64*)&mlds[rr][64 * p + c4];
            __hip_atomic_store((u64*)&mbuf[rr * MDIM + 64 * p + c4], v,
                               __ATOMIC_RELAXED, __HIP_MEMORY_SCOPE_AGENT);
        }
        asm volatile("s_waitcnt vmcnt(0)" ::: "memory");
        __syncthreads();              // S6: exports drained
        if (tid == 0)                 // arrive B
            __hip_atomic_fetch_add(ctr, 1u, __ATOMIC_RELAXED, __HIP_MEMORY_SCOPE_AGENT);

        // RTT window B: own-block m seed for t+1 (G1 continues, G23 starts)
        if (t + 1 < TLEN) {
            bf16x8 am0 = *(const bf16x8*)&mlds[l15][((2 * p + 0) & 15) * 32 + koff];
            bf16x8 am1 = *(const bf16x8*)&mlds[l15][((2 * p + 1) & 15) * 32 + koff];
            if (isG1) { mfma_a(accE, am0, wA[0]);  mfma_a(accO, am1, wA[1]); }
            else      { mfma_z(accE, am0, wA[0]);  mfma_z(accO, am1, wA[1]); }
        }
        if (tid == 0) {               // wait B
            u32 tgt = 16u * (u32)t + 16u;
            while (__hip_atomic_load(ctr, __ATOMIC_RELAXED, __HIP_MEMORY_SCOPE_AGENT) < tgt)
                __builtin_amdgcn_s_sleep(1);
        }
        __syncthreads();              // S7: release B
        for (int s = tid; s < 1792; s += 512) {   // gather peers' m'
            int j = 1 + (s >> 8);
            int k = s & 255;
            int q = (p + j) & 7;
            int rr = k >> 4, c4 = (k & 15) << 2;
            u64 v = __hip_atomic_load((const u64*)&mbuf[rr * MDIM + 64 * q + c4],
                                      __ATOMIC_RELAXED, __HIP_MEMORY_SCOPE_AGENT);
            *(u64*)&mlds[rr][64 * q + c4] = v;
        }
        __syncthreads();              // S8: mlds = m_{t+1} full
    }

    // ---- epilogue: group rep (p==0) computes out = m_T @ Wout^T + bout ----
    if (p == 0) {
        const int oc = 16 * w + l15;
        const __bf16* ro = WO + (size_t)oc * MDIM;
        f32x4 oe = {0, 0, 0, 0}, oo = {0, 0, 0, 0};
        #pragma unroll
        for (int j = 0; j < 16; ++j) {
            bf16x8 am = *(const bf16x8*)&mlds[l15][j * 32 + koff];
            bf16x8 bw = *(const bf16x8*)&ro[j * 32 + koff];
            if (j & 1) oo = mfma16(am, bw, oo); else oe = mfma16(am, bw, oe);
        }
        f32x4 oa = oe + oo;
        const float bo = bout[oc];
        #pragma unroll
        for (int r = 0; r < 4; ++r)
            out[(size_t)(row0 + 4 * l4 + r) * ODIM + oc] = oa[r] + bo;
    }
}

extern "C" void kernel_launch(void* const* d_in, const int* in_sizes, int n_in,
                              void* d_out, int out_size, void* d_ws, size_t ws_size,
                              hipStream_t stream)
{
    const float* x    = (const float*)d_in[0];
    const float* m0   = (const float*)d_in[1];
    const float* Wi2f = (const float*)d_in[2];
    const float* bi2f = (const float*)d_in[3];
    const float* Wm2f = (const float*)d_in[4];
    const float* bm2f = (const float*)d_in[5];
    const float* Wf2m = (const float*)d_in[6];
    const float* bf2m = (const float*)d_in[7];
    const float* Wm2m = (const float*)d_in[8];
    const float* bm2m = (const float*)d_in[9];
    const float* Wout = (const float*)d_in[10];
    const float* bout = (const float*)d_in[11];

    char* ws = (char*)d_ws;
    __bf16* WI  = (__bf16*)(ws + WS_WI);
    __bf16* W2F = (__bf16*)(ws + WS_W2F);
    __bf16* W2M = (__bf16*)(ws + WS_W2M);
    __bf16* WF2 = (__bf16*)(ws + WS_WF2);
    __bf16* WO  = (__bf16*)(ws + WS_WO);
    float*  b1  = (float*)(ws + WS_B1);
    float*  b23 = (float*)(ws + WS_B23);
    u32*    ctr = (u32*)(ws + WS_CTR);
    __bf16* fb  = (__bf16*)(ws + WS_FBUF);
    __bf16* mb  = (__bf16*)(ws + WS_MBUF);

    const int prep_total = N_WI + N_W2F + N_W2M + N_WF2 + N_WO + FDIM + MDIM + NGRP * 64;
    lmn_prep<<<(prep_total + 255) / 256, 256, 0, stream>>>(
        Wi2f, Wm2f, Wm2m, Wf2m, Wout, bi2f, bm2f, bf2m, bm2m,
        WI, W2F, W2M, WF2, WO, b1, b23, ctr);

    lmn_scan<<<NGRP * NCU, 512, 0, stream>>>(
        x, m0, WI, W2F, W2M, WF2, WO, b1, b23, bout, ctr, fb, mb, (float*)d_out);
}